// Round 1
// baseline (1783.527 us; speedup 1.0000x reference)
//
#include <hip/hip_runtime.h>
#include <math.h>

#define V_SIZE 50257
#define EMB 512
#define HID 512
#define NB 32
#define TT 128
#define NSTEP 127
#define G3H 1536
#define MROWS 4064   // NSTEP*NB
#define MPAD 4096
#define VPAD 50304   // 393*128
#define NT_V 393

typedef __attribute__((ext_vector_type(4))) float f32x4;
typedef __attribute__((ext_vector_type(8))) __bf16 bf16x8;
typedef __attribute__((ext_vector_type(4))) __bf16 bf16x4;

// ---------------- prep kernels ----------------

// emit_W fp32 [V,512] -> bf16 [VPAD,512], pad rows zero
__global__ void k_prep_emit(const float* __restrict__ src, __bf16* __restrict__ dst) {
    size_t total4 = (size_t)VPAD * 512 / 4;
    size_t real4  = (size_t)V_SIZE * 512 / 4;
    for (size_t i4 = (size_t)blockIdx.x * blockDim.x + threadIdx.x; i4 < total4;
         i4 += (size_t)gridDim.x * blockDim.x) {
        float4 v = (i4 < real4) ? ((const float4*)src)[i4] : make_float4(0.f,0.f,0.f,0.f);
        bf16x4 o = {(__bf16)v.x, (__bf16)v.y, (__bf16)v.z, (__bf16)v.w};
        ((bf16x4*)dst)[i4] = o;
    }
}

// W_ih fp32 [1536,512] -> bf16
__global__ void k_prep_wih(const float* __restrict__ src, __bf16* __restrict__ dst) {
    size_t total4 = (size_t)G3H * 512 / 4;
    for (size_t i4 = (size_t)blockIdx.x * blockDim.x + threadIdx.x; i4 < total4;
         i4 += (size_t)gridDim.x * blockDim.x) {
        float4 v = ((const float4*)src)[i4];
        bf16x4 o = {(__bf16)v.x, (__bf16)v.y, (__bf16)v.z, (__bf16)v.w};
        ((bf16x4*)dst)[i4] = o;
    }
}

// W_hhT[k][j] = W_hh[j][k]  (fp32, k in [0,512), j in [0,1536))
__global__ void k_prep_whh(const float* __restrict__ W, float* __restrict__ WT) {
    int idx = blockIdx.x * 256 + threadIdx.x;
    if (idx < 512 * G3H) {
        int k = idx / G3H;
        int j = idx - k * G3H;
        WT[idx] = W[(size_t)j * 512 + k];
    }
}

// embedding gather -> Xb bf16 [MPAD,512]; zero pad rows of Xb and Hs; init Hcur[0]
__global__ void k_prep_x(const int* __restrict__ words, const float* __restrict__ embed,
                         const float* __restrict__ h0, __bf16* __restrict__ Xb,
                         __bf16* __restrict__ Hs, float* __restrict__ Hcur) {
    int s = blockIdx.x;   // 0..127
    int n = blockIdx.y;   // 0..31
    int tid = threadIdx.x; // 128
    if (s < NSTEP) {
        int w = words[n * TT + s];
        size_t row = (size_t)(s * NB + n);
        const float4* src = (const float4*)(embed + (size_t)w * EMB);
        bf16x4* dst = (bf16x4*)(Xb + row * EMB);
        for (int c = tid; c < EMB / 4; c += 128) {
            float4 v = src[c];
            bf16x4 o = {(__bf16)v.x, (__bf16)v.y, (__bf16)v.z, (__bf16)v.w};
            dst[c] = o;
        }
    } else {
        size_t row = (size_t)(MROWS + n);
        bf16x4 z = {(__bf16)0.f, (__bf16)0.f, (__bf16)0.f, (__bf16)0.f};
        for (int c = tid; c < EMB / 4; c += 128) {
            ((bf16x4*)(Xb + row * EMB))[c] = z;
            ((bf16x4*)(Hs + row * HID))[c] = z;
        }
        for (int c = tid; c < HID; c += 128) Hcur[n * HID + c] = h0[n * HID + c];
    }
}

// ---------------- MFMA GEMM core: C[m][n] = sum_k A[m][k]*B[n][k] (both K-major bf16) ----------------

__device__ __forceinline__ void gemm_mainloop(const __bf16* __restrict__ A,
                                              const __bf16* __restrict__ B,
                                              int mBase, int nBase, f32x4 acc[4][4],
                                              __bf16* As, __bf16* Bs) {
    const int tid = threadIdx.x;            // 256
    const int lane = tid & 63;
    const int wave = tid >> 6;              // 0..3
    const int wm = wave >> 1, wn = wave & 1;
    const int lane15 = lane & 15, quad = lane >> 4;
    for (int kc = 0; kc < 512; kc += 64) {
        __syncthreads();
#pragma unroll
        for (int t = 0; t < 4; ++t) {
            int c = tid + t * 256;          // 0..1023
            int row = c >> 3, ci = c & 7;
            *(uint4*)(&As[row * 72 + ci * 8]) =
                *(const uint4*)(A + (size_t)(mBase + row) * 512 + kc + ci * 8);
            *(uint4*)(&Bs[row * 72 + ci * 8]) =
                *(const uint4*)(B + (size_t)(nBase + row) * 512 + kc + ci * 8);
        }
        __syncthreads();
#pragma unroll
        for (int ks = 0; ks < 64; ks += 32) {
            bf16x8 af[4], bfr[4];
#pragma unroll
            for (int mi = 0; mi < 4; ++mi)
                af[mi] = *(const bf16x8*)(&As[(wm * 64 + mi * 16 + lane15) * 72 + ks + quad * 8]);
#pragma unroll
            for (int ni = 0; ni < 4; ++ni)
                bfr[ni] = *(const bf16x8*)(&Bs[(wn * 64 + ni * 16 + lane15) * 72 + ks + quad * 8]);
#pragma unroll
            for (int mi = 0; mi < 4; ++mi)
#pragma unroll
                for (int ni = 0; ni < 4; ++ni)
                    acc[mi][ni] = __builtin_amdgcn_mfma_f32_16x16x32_bf16(
                        af[mi], bfr[ni], acc[mi][ni], 0, 0, 0);
        }
    }
}

// gi = Xb @ W_ih^T + b_ih (+ b_hh for r,z gates)   -> fp32 [MPAD][1536]
__global__ __launch_bounds__(256) void k_gemm_gi(const __bf16* __restrict__ Xb,
                                                 const __bf16* __restrict__ Wihb,
                                                 const float* __restrict__ b_ih,
                                                 const float* __restrict__ b_hh,
                                                 float* __restrict__ gi) {
    __shared__ __bf16 As[128 * 72];
    __shared__ __bf16 Bs[128 * 72];
    f32x4 acc[4][4];
    f32x4 z = {0.f, 0.f, 0.f, 0.f};
#pragma unroll
    for (int mi = 0; mi < 4; ++mi)
#pragma unroll
        for (int ni = 0; ni < 4; ++ni) acc[mi][ni] = z;
    int mBase = blockIdx.x * 128, nBase = blockIdx.y * 128;
    gemm_mainloop(Xb, Wihb, mBase, nBase, acc, As, Bs);
    const int tid = threadIdx.x, lane = tid & 63, wave = tid >> 6;
    const int wm = wave >> 1, wn = wave & 1, lane15 = lane & 15, quad = lane >> 4;
#pragma unroll
    for (int ni = 0; ni < 4; ++ni) {
        int col = nBase + wn * 64 + ni * 16 + lane15;
        float bias = b_ih[col] + (col < 1024 ? b_hh[col] : 0.0f);
#pragma unroll
        for (int mi = 0; mi < 4; ++mi) {
            int rowb = wm * 64 + mi * 16 + quad * 4;
#pragma unroll
            for (int r = 0; r < 4; ++r) {
                int m = mBase + rowb + r;
                gi[(size_t)m * G3H + col] = acc[mi][ni][r] + bias;
            }
        }
    }
}

// emit GEMM with fused per-tile logsumexp partials: partials[m][nT] = (max, sumexp)
__global__ __launch_bounds__(256) void k_gemm_emit(const __bf16* __restrict__ Hs,
                                                   const __bf16* __restrict__ Wemb,
                                                   const float* __restrict__ emit_b,
                                                   float2* __restrict__ partials) {
    __shared__ __bf16 As[128 * 72];
    __shared__ __bf16 Bs[128 * 72];
    __shared__ float2 red[128][2];
    f32x4 acc[4][4];
    f32x4 z = {0.f, 0.f, 0.f, 0.f};
#pragma unroll
    for (int mi = 0; mi < 4; ++mi)
#pragma unroll
        for (int ni = 0; ni < 4; ++ni) acc[mi][ni] = z;
    int mBase = blockIdx.x * 128;
    int nT = blockIdx.y;
    int nBase = nT * 128;
    gemm_mainloop(Hs, Wemb, mBase, nBase, acc, As, Bs);
    const int tid = threadIdx.x, lane = tid & 63, wave = tid >> 6;
    const int wm = wave >> 1, wn = wave & 1, lane15 = lane & 15, quad = lane >> 4;
    const float NINF = -__builtin_inff();
    float bv[4];
    bool valid[4];
#pragma unroll
    for (int ni = 0; ni < 4; ++ni) {
        int col = nBase + wn * 64 + ni * 16 + lane15;
        valid[ni] = (col < V_SIZE);
        bv[ni] = valid[ni] ? emit_b[col] : 0.0f;
    }
#pragma unroll
    for (int mi = 0; mi < 4; ++mi) {
#pragma unroll
        for (int r = 0; r < 4; ++r) {
            float vals[4];
            float vmax = NINF;
#pragma unroll
            for (int ni = 0; ni < 4; ++ni) {
                float v = acc[mi][ni][r] + bv[ni];
                if (!valid[ni]) v = NINF;
                vals[ni] = v;
                vmax = fmaxf(vmax, v);
            }
#pragma unroll
            for (int off = 1; off < 16; off <<= 1)
                vmax = fmaxf(vmax, __shfl_xor(vmax, off));
            float ssum = 0.f;
#pragma unroll
            for (int ni = 0; ni < 4; ++ni) ssum += expf(vals[ni] - vmax);
#pragma unroll
            for (int off = 1; off < 16; off <<= 1) ssum += __shfl_xor(ssum, off);
            if (lane15 == 0) {
                int rl = wm * 64 + mi * 16 + quad * 4 + r;
                red[rl][wn] = make_float2(vmax, ssum);
            }
        }
    }
    __syncthreads();
    if (tid < 128) {
        float2 a = red[tid][0], b2 = red[tid][1];
        float M = fmaxf(a.x, b2.x);
        float S = a.y * expf(a.x - M) + b2.y * expf(b2.x - M);
        partials[(size_t)(mBase + tid) * NT_V + nT] = make_float2(M, S);
    }
}

// ---------------- sequential GRU step ----------------
// grid (32 n, 4 jq) x 512 threads (j_loc 128 x kq 4)
__global__ __launch_bounds__(512) void k_gru_step(const float* __restrict__ gi,
                                                  const float* __restrict__ WhhT,
                                                  const float* __restrict__ b_hh,
                                                  float* __restrict__ Hcur,
                                                  __bf16* __restrict__ Hs, int s) {
    int n = blockIdx.x, jq = blockIdx.y;
    int tid = threadIdx.x;
    int j_loc = tid & 127, kq = tid >> 7;
    __shared__ float hrow[512];
    __shared__ float part[3][4][128];
    const float* hprev = Hcur + (size_t)(s & 1) * NB * HID + (size_t)n * HID;
    if (tid < 512) hrow[tid] = hprev[tid];
    __syncthreads();
    int j = jq * 128 + j_loc;
    float ar = 0.f, az = 0.f, an = 0.f;
    int k0 = kq * 128;
#pragma unroll 4
    for (int k = k0; k < k0 + 128; ++k) {
        float hk = hrow[k];
        const float* wrow = WhhT + (size_t)k * G3H;
        ar += hk * wrow[j];
        az += hk * wrow[512 + j];
        an += hk * wrow[1024 + j];
    }
    part[0][kq][j_loc] = ar;
    part[1][kq][j_loc] = az;
    part[2][kq][j_loc] = an;
    __syncthreads();
    if (tid < 128) {
        float gr = 0.f, gz = 0.f, gn = 0.f;
#pragma unroll
        for (int q = 0; q < 4; ++q) {
            gr += part[0][q][tid];
            gz += part[1][q][tid];
            gn += part[2][q][tid];
        }
        int jj = jq * 128 + tid;
        const float* g = gi + (size_t)(s * NB + n) * G3H;
        float ir = g[jj], iz = g[512 + jj], in_ = g[1024 + jj];
        float r = 1.f / (1.f + expf(-(ir + gr)));
        float zg = 1.f / (1.f + expf(-(iz + gz)));
        float nn = tanhf(in_ + r * (gn + b_hh[1024 + jj]));
        float hp = hrow[jj];
        float hn = (1.f - zg) * nn + zg * hp;
        Hcur[(size_t)((s + 1) & 1) * NB * HID + (size_t)n * HID + jj] = hn;
        Hs[(size_t)(s * NB + n) * HID + jj] = (__bf16)hn;
    }
}

// ---------------- per-row log-likelihood ----------------
__global__ __launch_bounds__(128) void k_row_ll(const float2* __restrict__ partials,
                                                const __bf16* __restrict__ Hs,
                                                const __bf16* __restrict__ Wemb,
                                                const float* __restrict__ emit_b,
                                                const int* __restrict__ words,
                                                float* __restrict__ lls) {
    int s = blockIdx.x, n = blockIdx.y;
    int m = s * NB + n;
    int tid = threadIdx.x;
    int lane = tid & 63, w = tid >> 6;
    __shared__ float sm[2], ss[2], sd[2];
    const float2* prow = partials + (size_t)m * NT_V;
    float M = -__builtin_inff();
    for (int i = tid; i < NT_V; i += 128) M = fmaxf(M, prow[i].x);
#pragma unroll
    for (int off = 1; off < 64; off <<= 1) M = fmaxf(M, __shfl_xor(M, off));
    if (lane == 0) sm[w] = M;
    __syncthreads();
    M = fmaxf(sm[0], sm[1]);
    float S = 0.f;
    for (int i = tid; i < NT_V; i += 128) {
        float2 p = prow[i];
        S += p.y * expf(p.x - M);
    }
#pragma unroll
    for (int off = 1; off < 64; off <<= 1) S += __shfl_xor(S, off);
    if (lane == 0) ss[w] = S;
    __syncthreads();
    S = ss[0] + ss[1];
    int tw = words[n * TT + s + 1];
    float d = 0.f;
    const __bf16* hr = Hs + (size_t)m * HID;
    const __bf16* wr = Wemb + (size_t)tw * HID;
    for (int k = tid; k < HID; k += 128) d += (float)hr[k] * (float)wr[k];
#pragma unroll
    for (int off = 1; off < 64; off <<= 1) d += __shfl_xor(d, off);
    if (lane == 0) sd[w] = d;
    __syncthreads();
    if (tid == 0) {
        float dt = sd[0] + sd[1];
        lls[m] = dt + emit_b[tw] - (M + logf(S));
    }
}

// ---------------- final reduce ----------------
__global__ __launch_bounds__(128) void k_final(const float* __restrict__ lls,
                                               const float* __restrict__ Hcur,
                                               float* __restrict__ out) {
    int n = blockIdx.x;
    int tid = threadIdx.x;
    float s = 0.f;
    for (int i = tid; i < NSTEP; i += 128) s += lls[i * NB + n];
#pragma unroll
    for (int off = 1; off < 64; off <<= 1) s += __shfl_xor(s, off);
    __shared__ float t2[2];
    if ((tid & 63) == 0) t2[tid >> 6] = s;
    __syncthreads();
    if (tid == 0) out[n] = (t2[0] + t2[1]) / (float)NSTEP;
    const float* hf = Hcur + (size_t)NB * HID + (size_t)n * HID;  // parity 1 after 127 steps
    for (int i = tid; i < HID; i += 128) out[32 + n * HID + i] = hf[i];
}

// ---------------- launch ----------------
extern "C" void kernel_launch(void* const* d_in, const int* in_sizes, int n_in,
                              void* d_out, int out_size, void* d_ws, size_t ws_size,
                              hipStream_t stream) {
    const int*   words   = (const int*)d_in[0];
    const float* hidden0 = (const float*)d_in[1];
    const float* embed_W = (const float*)d_in[2];
    const float* W_ih    = (const float*)d_in[3];
    const float* W_hh    = (const float*)d_in[4];
    const float* b_ih    = (const float*)d_in[5];
    const float* b_hh    = (const float*)d_in[6];
    const float* emit_W  = (const float*)d_in[7];
    const float* emit_b  = (const float*)d_in[8];
    float* out = (float*)d_out;

    char* p = (char*)d_ws;
    auto alloc = [&](size_t bytes) {
        void* r = (void*)p;
        p += (bytes + 255) & ~(size_t)255;
        return r;
    };
    __bf16* emit_Wb = (__bf16*)alloc((size_t)VPAD * 512 * 2);
    __bf16* Xb      = (__bf16*)alloc((size_t)MPAD * 512 * 2);
    __bf16* Wihb    = (__bf16*)alloc((size_t)G3H * 512 * 2);
    float*  WhhT    = (float*)alloc((size_t)512 * G3H * 4);
    float*  gi      = (float*)alloc((size_t)MPAD * G3H * 4);
    __bf16* Hs      = (__bf16*)alloc((size_t)MPAD * 512 * 2);
    float*  Hcur    = (float*)alloc((size_t)2 * NB * HID * 4);
    float2* partials= (float2*)alloc((size_t)MPAD * NT_V * 8);
    float*  lls     = (float*)alloc((size_t)MROWS * 4);

    k_prep_emit<<<4096, 256, 0, stream>>>(emit_W, emit_Wb);
    k_prep_x<<<dim3(128, 32), 128, 0, stream>>>(words, embed_W, hidden0, Xb, Hs, Hcur);
    k_prep_wih<<<768, 256, 0, stream>>>(W_ih, Wihb);
    k_prep_whh<<<3072, 256, 0, stream>>>(W_hh, WhhT);

    k_gemm_gi<<<dim3(32, 12), 256, 0, stream>>>(Xb, Wihb, b_ih, b_hh, gi);

    for (int s = 0; s < NSTEP; ++s)
        k_gru_step<<<dim3(32, 4), 512, 0, stream>>>(gi, WhhT, b_hh, Hcur, Hs, s);

    k_gemm_emit<<<dim3(32, NT_V), 256, 0, stream>>>(Hs, emit_Wb, emit_b, partials);
    k_row_ll<<<dim3(NSTEP, 32), 128, 0, stream>>>(partials, Hs, emit_Wb, emit_b, words, lls);
    k_final<<<32, 128, 0, stream>>>(lls, Hcur, out);
}